// Round 17
// baseline (311.233 us; speedup 1.0000x reference)
//
#include <hip/hip_runtime.h>

// AttentionActorCritic fused forward, MI355X (gfx950).
// Round 17: r16 with launch_bounds(512,2). r12-r16 all spilled the X' f32x4
// registers held across barrier A (compiler chose VGPR=64 under (512,4) and
// scratch-spilled ~45KB/block: WRITE_SIZE 183MB). LDS caps us at 2 blocks/CU
// anyway, so a 256-VGPR cap is free. Everything else identical to r16.

typedef __bf16 bhalf;
typedef __bf16 bhalf4 __attribute__((ext_vector_type(4)));
typedef __bf16 bhalf8 __attribute__((ext_vector_type(8)));
typedef float f32x4 __attribute__((ext_vector_type(4)));
typedef float f32x2 __attribute__((ext_vector_type(2)));

#define DEV static __device__ __forceinline__

DEV f32x4 mfma16(bhalf8 a, bhalf8 b, f32x4 c) {
  return __builtin_amdgcn_mfma_f32_16x16x32_bf16(a, b, c, 0, 0, 0);
}

// s_x swizzle: row stride 32 elems (64B = 16 banks). XOR 16B slot with
// (row>>1)&3 so the 8 rows sharing a bank-base spread over all 4 slots.
DEV int sxo(int row, int col) { return row * 32 + (col ^ (((row >> 1) & 3) << 3)); }

// ---------------- pointer bundle ----------------
struct Ptrs {
  const float* state;
  const float *p_g1, *p_b1, *p_f1b, *p_f2b, *p_g2, *p_b2, *p_out_b;
  const float *s_g1, *s_b1, *s_f1b, *s_f2b, *s_g2, *s_b2, *s_out_b;
  const float *d1_b, *d2_b, *pi_w, *pi_b, *v_w, *v_b;
  const bhalf *A_qp, *A_xp, *w_o, *w_f1, *w_f2, *w_out;
  const bhalf *A_qs, *A_xs, *w_o2, *w_f12, *w_f22, *w_out2;
  const bhalf *A_e, *w_d1, *w_d2;
  float* out;
};

// ---------------- prep: fp32 -> bf16 conversions ----------------
struct PrepArgs {
  const float* src[10];
  int len[10];
  int dstOff[10];
  bhalf* dst;
};

__global__ void prep_convert(PrepArgs a) {
  int idx = blockIdx.x * blockDim.x + threadIdx.x;
  int off = 0;
#pragma unroll
  for (int i = 0; i < 10; ++i) {
    int n = a.len[i];
    if (idx >= off && idx < off + n) a.dst[a.dstOff[i] + idx - off] = (bhalf)a.src[i][idx - off];
    off += n;
  }
}

// ---------------- prep: effective (folded) weight matrices ----------------
struct EffArgs {
  const float *p_qkv_w, *p_in_w, *p_in_b, *p_qkv_b, *p_o_b;
  const float *s_qkv_w, *s_in_w, *s_in_b, *s_qkv_b, *s_o_b;
  const float *e_w, *e_b;
  bhalf* dst;
};

__global__ void prep_eff(EffArgs a) {
  int tid = threadIdx.x;
  if (tid < 96) {  // A_qp row o
    const float* wq = a.p_qkv_w + tid * 32;
    float w0 = 0.f, w1 = 0.f, be = 0.f;
    for (int e = 0; e < 32; ++e) {
      w0 += wq[e] * a.p_in_w[e * 2];
      w1 += wq[e] * a.p_in_w[e * 2 + 1];
      be += wq[e] * a.p_in_b[e];
    }
    be += a.p_qkv_b[tid];
    bhalf* d = a.dst + tid * 32;
    for (int k = 0; k < 32; ++k) d[k] = (bhalf)0.f;
    d[0] = (bhalf)w0; d[1] = (bhalf)w1; d[2] = (bhalf)be;
  } else if (tid < 192) {  // A_qs row o
    int o = tid - 96;
    const float* wq = a.s_qkv_w + o * 32;
    float wf[4] = {0.f, 0.f, 0.f, 0.f}, be = 0.f;
    for (int e = 0; e < 32; ++e) {
      for (int f = 0; f < 4; ++f) wf[f] += wq[e] * a.s_in_w[e * 4 + f];
      be += wq[e] * a.s_in_b[e];
    }
    be += a.s_qkv_b[o];
    bhalf* d = a.dst + 35840 + o * 32;
    for (int k = 0; k < 32; ++k) d[k] = (bhalf)0.f;
    for (int f = 0; f < 4; ++f) d[f] = (bhalf)wf[f];
    d[4] = (bhalf)be;
  } else if (tid < 224) {  // A_xp row e
    int e = tid - 192;
    bhalf* d = a.dst + 3072 + e * 32;
    for (int k = 0; k < 32; ++k) d[k] = (bhalf)0.f;
    d[0] = (bhalf)a.p_in_w[e * 2];
    d[1] = (bhalf)a.p_in_w[e * 2 + 1];
    d[2] = (bhalf)(a.p_in_b[e] + a.p_o_b[e]);
  } else if (tid < 256) {  // A_xs row e
    int e = tid - 224;
    bhalf* d = a.dst + 38912 + e * 32;
    for (int k = 0; k < 32; ++k) d[k] = (bhalf)0.f;
    for (int f = 0; f < 4; ++f) d[f] = (bhalf)a.s_in_w[e * 4 + f];
    d[4] = (bhalf)(a.s_in_b[e] + a.s_o_b[e]);
  } else if (tid < 384) {  // A_e row o
    int o = tid - 256;
    bhalf* d = a.dst + 51200 + o * 32;
    for (int k = 0; k < 32; ++k) d[k] = (bhalf)0.f;
    for (int k = 0; k < 8; ++k) d[k] = (bhalf)a.e_w[o * 8 + k];
    d[8] = (bhalf)a.e_b[o];
  }
}

// ---------------- phase-1 tile: one bf build -> 6 QKV (LDS) + 2 X' (regs) ----------------
DEV void p1_tile(const Ptrs& P, bhalf* s_q, int tile, int s0, int l15, int lq,
                 f32x4& cx0, f32x4& cx1) {
  const bool sw = tile >= 14;
  bhalf8 bf;
#pragma unroll
  for (int k = 0; k < 8; ++k) bf[k] = (bhalf)0.f;
  if (lq == 0) {
    int s = (tile & 1) * 16 + l15;
    const float* st = &P.state[(size_t)(s0 + s) * 30];
    if (!sw) {
      int t = tile >> 1;
      f32x2 v = *(const f32x2*)(st + 2 * t);
      bf[0] = (bhalf)v[0]; bf[1] = (bhalf)v[1]; bf[2] = (bhalf)1.0f;
    } else {
      int ts = (tile - 14) >> 1;
      f32x2 v0 = *(const f32x2*)(st + 14 + 4 * ts);
      f32x2 v1 = *(const f32x2*)(st + 16 + 4 * ts);
      bf[0] = (bhalf)v0[0]; bf[1] = (bhalf)v0[1];
      bf[2] = (bhalf)v1[0]; bf[3] = (bhalf)v1[1];
      bf[4] = (bhalf)1.0f;
    }
  }
  const bhalf* Aq = sw ? P.A_qs : P.A_qp;
  const bhalf* Ax = sw ? P.A_xs : P.A_xp;
  const int row = tile * 16 + l15;
#pragma unroll
  for (int n = 0; n < 6; ++n) {
    f32x4 c = {0.f, 0.f, 0.f, 0.f};
    c = mfma16(*(const bhalf8*)&Aq[(n * 16 + l15) * 32 + lq * 8], bf, c);
    bhalf4 o;
#pragma unroll
    for (int j = 0; j < 4; ++j) o[j] = (bhalf)c[j];
    *(bhalf4*)&s_q[row * 104 + n * 16 + lq * 4] = o;
  }
  cx0 = f32x4{0.f, 0.f, 0.f, 0.f};
  cx1 = f32x4{0.f, 0.f, 0.f, 0.f};
  cx0 = mfma16(*(const bhalf8*)&Ax[l15 * 32 + lq * 8], bf, cx0);
  cx1 = mfma16(*(const bhalf8*)&Ax[(16 + l15) * 32 + lq * 8], bf, cx1);
}

// ---------------- attention: reg output, qkv stride 104, token stride 32 rows ----------------
template <int T>
DEV bhalf8 attn_head(const bhalf* qkv, int rowbase, int a, int s, int h) {
  const bhalf* base = &qkv[(rowbase + s) * 104 + h * 8];
  const int rstep = 32 * 104;
  bhalf8 kf[T];
#pragma unroll
  for (int b = 0; b < T; ++b) kf[b] = *(const bhalf8*)(base + b * rstep + 32);
  bhalf8 qv = *(const bhalf8*)(base + a * rstep);
  float q[8];
#pragma unroll
  for (int i = 0; i < 8; ++i) q[i] = (float)qv[i];
  float sc[T];
  float mx = -1e30f;
#pragma unroll
  for (int b = 0; b < T; ++b) {
    float d = 0.f;
#pragma unroll
    for (int i = 0; i < 8; ++i) d += q[i] * (float)kf[b][i];
    d *= 0.35355339059327378f;  // 1/sqrt(8)
    sc[b] = d;
    mx = fmaxf(mx, d);
  }
  bhalf8 vf[T];
#pragma unroll
  for (int b = 0; b < T; ++b) vf[b] = *(const bhalf8*)(base + b * rstep + 64);
  float sum = 0.f;
#pragma unroll
  for (int b = 0; b < T; ++b) { sc[b] = __expf(sc[b] - mx); sum += sc[b]; }
  float inv = 1.f / sum;
  float o[8] = {0.f, 0.f, 0.f, 0.f, 0.f, 0.f, 0.f, 0.f};
#pragma unroll
  for (int b = 0; b < T; ++b) {
    float w = sc[b] * inv;
#pragma unroll
    for (int i = 0; i < 8; ++i) o[i] += w * (float)vf[b][i];
  }
  bhalf8 ov;
#pragma unroll
  for (int i = 0; i < 8; ++i) ov[i] = (bhalf)o[i];
  return ov;
}

// ---------------- fused encoder tile-chain (X' C-init from registers) ----------------
template <int T>
DEV void enc_tile(const bhalf* s_q, bhalf* s_x, int tile, int l15, int lq,
                  f32x4 c0, f32x4 c1,
                  const bhalf* wo, const bhalf* wf1, const bhalf* wf2,
                  const float* g1, const float* b1, const float* f1b,
                  const float* f2b, const float* g2, const float* b2) {
  const int rowbase = (T == 7) ? 0 : 224;
  const int a = (T == 7) ? (tile >> 1) : ((tile - 14) >> 1);
  const int s = (tile & 1) * 16 + l15;
  bhalf8 ov = attn_head<T>(s_q, rowbase, a, s, lq);
  const int row = tile * 16 + l15;
  // o-proj; C-init = X' (f32, includes o_b) from registers
  c0 = mfma16(*(const bhalf8*)&wo[l15 * 32 + lq * 8], ov, c0);
  c1 = mfma16(*(const bhalf8*)&wo[(16 + l15) * 32 + lq * 8], ov, c1);
  // LN1 in-register
  float sum = 0.f, ss = 0.f;
#pragma unroll
  for (int j = 0; j < 4; ++j) { sum += c0[j] + c1[j]; ss += c0[j] * c0[j] + c1[j] * c1[j]; }
  sum += __shfl_xor(sum, 16); sum += __shfl_xor(sum, 32);
  ss += __shfl_xor(ss, 16); ss += __shfl_xor(ss, 32);
  float mu = sum * 0.03125f;
  float rs = rsqrtf(ss * 0.03125f - mu * mu + 1e-5f);
  f32x4 gg0 = *(const f32x4*)&g1[lq * 4], gg1 = *(const f32x4*)&g1[16 + lq * 4];
  f32x4 hb0 = *(const f32x4*)&b1[lq * 4], hb1 = *(const f32x4*)&b1[16 + lq * 4];
  float xn[8];
#pragma unroll
  for (int j = 0; j < 4; ++j) {
    xn[j] = (c0[j] - mu) * rs * gg0[j] + hb0[j];
    xn[4 + j] = (c1[j] - mu) * rs * gg1[j] + hb1[j];
  }
  bhalf4 p0, p1;
#pragma unroll
  for (int j = 0; j < 4; ++j) { p0[j] = (bhalf)xn[j]; p1[j] = (bhalf)xn[4 + j]; }
  *(bhalf4*)&s_x[sxo(row, lq * 4)] = p0;
  *(bhalf4*)&s_x[sxo(row, 16 + lq * 4)] = p1;
  bhalf8 bfr = *(const bhalf8*)&s_x[sxo(row, lq * 8)];
  // FF1 + relu (bounce via s_x; residual xn stays in regs)
  c0 = f32x4{0.f, 0.f, 0.f, 0.f};
  c1 = f32x4{0.f, 0.f, 0.f, 0.f};
  c0 = mfma16(*(const bhalf8*)&wf1[l15 * 32 + lq * 8], bfr, c0);
  c1 = mfma16(*(const bhalf8*)&wf1[(16 + l15) * 32 + lq * 8], bfr, c1);
  f32x4 fb0 = *(const f32x4*)&f1b[lq * 4], fb1 = *(const f32x4*)&f1b[16 + lq * 4];
#pragma unroll
  for (int j = 0; j < 4; ++j) {
    p0[j] = (bhalf)fmaxf(c0[j] + fb0[j], 0.f);
    p1[j] = (bhalf)fmaxf(c1[j] + fb1[j], 0.f);
  }
  *(bhalf4*)&s_x[sxo(row, lq * 4)] = p0;
  *(bhalf4*)&s_x[sxo(row, 16 + lq * 4)] = p1;
  bfr = *(const bhalf8*)&s_x[sxo(row, lq * 8)];
  // FF2 with C-init = xn + f2b (residual + bias), then LN2 -> s_x
  f32x4 f20 = *(const f32x4*)&f2b[lq * 4], f21 = *(const f32x4*)&f2b[16 + lq * 4];
#pragma unroll
  for (int j = 0; j < 4; ++j) { c0[j] = xn[j] + f20[j]; c1[j] = xn[4 + j] + f21[j]; }
  c0 = mfma16(*(const bhalf8*)&wf2[l15 * 32 + lq * 8], bfr, c0);
  c1 = mfma16(*(const bhalf8*)&wf2[(16 + l15) * 32 + lq * 8], bfr, c1);
  sum = 0.f; ss = 0.f;
#pragma unroll
  for (int j = 0; j < 4; ++j) { sum += c0[j] + c1[j]; ss += c0[j] * c0[j] + c1[j] * c1[j]; }
  sum += __shfl_xor(sum, 16); sum += __shfl_xor(sum, 32);
  ss += __shfl_xor(ss, 16); ss += __shfl_xor(ss, 32);
  mu = sum * 0.03125f;
  rs = rsqrtf(ss * 0.03125f - mu * mu + 1e-5f);
  f32x4 g20 = *(const f32x4*)&g2[lq * 4], g21 = *(const f32x4*)&g2[16 + lq * 4];
  f32x4 b20 = *(const f32x4*)&b2[lq * 4], b21 = *(const f32x4*)&b2[16 + lq * 4];
#pragma unroll
  for (int j = 0; j < 4; ++j) {
    p0[j] = (bhalf)((c0[j] - mu) * rs * g20[j] + b20[j]);
    p1[j] = (bhalf)((c1[j] - mu) * rs * g21[j] + b21[j]);
  }
  *(bhalf4*)&s_x[sxo(row, lq * 4)] = p0;
  *(bhalf4*)&s_x[sxo(row, 16 + lq * 4)] = p1;
}

// ---------------- main fused kernel: 32 samples/block ----------------
__launch_bounds__(512, 2)
__global__ void aac_main(Ptrs P) {
  // 18432 + 59904 = 78336 B -> 2 blocks/CU (LDS-bound); VGPR cap 256 -> no spill
  __shared__ __align__(16) bhalf s_x[288 * 32];   // LN2 out + chain bounces (swizzled)
  __shared__ __align__(16) bhalf s_q[288 * 104];  // qkv; aliases xcat/h1/h2

  bhalf* xcat = s_q;                   // [32][408] elems 0..13055
  bhalf* h1 = s_q + 13056;             // [32][136]
  float* h2 = (float*)(s_q + 17408);   // [32][140] f32

  const int tid = threadIdx.x;
  const int wave = tid >> 6, lane = tid & 63;
  const int l15 = lane & 15, lq = lane >> 4;
  const int s0 = blockIdx.x * 32;

  // ---- phase 1: per-wave chain tiles; QKV -> LDS, X' -> regs ----
  f32x4 xA0, xA1, xB0, xB1, xC0, xC1;
  p1_tile(P, s_q, wave, s0, l15, lq, xA0, xA1);
  p1_tile(P, s_q, wave + 8, s0, l15, lq, xB0, xB1);
  if (wave < 2) p1_tile(P, s_q, 16 + wave, s0, l15, lq, xC0, xC1);
  __syncthreads();  // A

  // ---- fused encoder: 18 tile-chains, 2-3 independent chains per wave ----
  enc_tile<7>(s_q, s_x, wave, l15, lq, xA0, xA1,
              P.w_o, P.w_f1, P.w_f2, P.p_g1, P.p_b1, P.p_f1b, P.p_f2b, P.p_g2, P.p_b2);
  if (wave < 6) {
    enc_tile<7>(s_q, s_x, wave + 8, l15, lq, xB0, xB1,
                P.w_o, P.w_f1, P.w_f2, P.p_g1, P.p_b1, P.p_f1b, P.p_f2b, P.p_g2, P.p_b2);
  } else {
    enc_tile<2>(s_q, s_x, wave + 8, l15, lq, xB0, xB1,
                P.w_o2, P.w_f12, P.w_f22, P.s_g1, P.s_b1, P.s_f1b, P.s_f2b, P.s_g2, P.s_b2);
  }
  if (wave < 2) {
    enc_tile<2>(s_q, s_x, 16 + wave, l15, lq, xC0, xC1,
                P.w_o2, P.w_f12, P.w_f22, P.s_g1, P.s_b1, P.s_f1b, P.s_f2b, P.s_g2, P.s_b2);
  }
  __syncthreads();  // B

  // ---- out_gemm + st_emb -> xcat (48 jobs, 6/wave) ----
#pragma unroll
  for (int k = 0; k < 2; ++k) {  // power out
    int f = wave + 8 * k;
    int n = f >> 1, m = f & 1;
    f32x4 c = {0.f, 0.f, 0.f, 0.f};
#pragma unroll
    for (int t = 0; t < 7; ++t) {
      bhalf8 a = *(const bhalf8*)&P.w_out[(n * 16 + l15) * 224 + t * 32 + lq * 8];
      bhalf8 b = *(const bhalf8*)&s_x[sxo(t * 32 + m * 16 + l15, lq * 8)];
      c = mfma16(a, b, c);
    }
    int oc = n * 16 + lq * 4;
    f32x4 bias = *(const f32x4*)&P.p_out_b[oc];
    bhalf4 o;
#pragma unroll
    for (int j = 0; j < 4; ++j) o[j] = (bhalf)fmaxf(c[j] + bias[j], 0.f);
    *(bhalf4*)&xcat[(m * 16 + l15) * 408 + oc] = o;
  }
#pragma unroll
  for (int k = 0; k < 2; ++k) {  // sword out
    int g = wave + 8 * k;
    int n = g >> 1, m = g & 1;
    f32x4 c = {0.f, 0.f, 0.f, 0.f};
#pragma unroll
    for (int t = 0; t < 2; ++t) {
      bhalf8 a = *(const bhalf8*)&P.w_out2[(n * 16 + l15) * 64 + t * 32 + lq * 8];
      bhalf8 b = *(const bhalf8*)&s_x[sxo(224 + t * 32 + m * 16 + l15, lq * 8)];
      c = mfma16(a, b, c);
    }
    int oc = n * 16 + lq * 4;
    f32x4 bias = *(const f32x4*)&P.s_out_b[oc];
    bhalf4 o;
#pragma unroll
    for (int j = 0; j < 4; ++j) o[j] = (bhalf)fmaxf(c[j] + bias[j], 0.f);
    *(bhalf4*)&xcat[(m * 16 + l15) * 408 + 128 + oc] = o;
  }
#pragma unroll
  for (int k = 0; k < 2; ++k) {  // st_emb
    int g = wave + 8 * k;
    int n = g >> 1, m = g & 1;
    int s = m * 16 + l15;
    bhalf8 bf;
#pragma unroll
    for (int kk = 0; kk < 8; ++kk) bf[kk] = (bhalf)0.f;
    if (lq == 0) {
      const float* st = &P.state[(size_t)(s0 + s) * 30 + 22];
#pragma unroll
      for (int kk = 0; kk < 4; ++kk) {
        f32x2 v = *(const f32x2*)(st + 2 * kk);
        bf[2 * kk] = (bhalf)v[0];
        bf[2 * kk + 1] = (bhalf)v[1];
      }
    } else if (lq == 1) {
      bf[0] = (bhalf)1.0f;
    }
    bhalf8 a = *(const bhalf8*)&P.A_e[(n * 16 + l15) * 32 + lq * 8];
    f32x4 c = {0.f, 0.f, 0.f, 0.f};
    c = mfma16(a, bf, c);
    bhalf4 o;
#pragma unroll
    for (int j = 0; j < 4; ++j) o[j] = (bhalf)fmaxf(c[j], 0.f);
    *(bhalf4*)&xcat[s * 408 + 256 + n * 16 + lq * 4] = o;
  }
  __syncthreads();  // C

  // ---- d1: 2 independent jobs/wave (m=0,1; n=wave) -> h1 ----
#pragma unroll
  for (int m = 0; m < 2; ++m) {
    int n = wave;
    f32x4 c = {0.f, 0.f, 0.f, 0.f};
#pragma unroll
    for (int ks = 0; ks < 12; ++ks) {
      bhalf8 a = *(const bhalf8*)&P.w_d1[(n * 16 + l15) * 384 + ks * 32 + lq * 8];
      bhalf8 b = *(const bhalf8*)&xcat[(m * 16 + l15) * 408 + ks * 32 + lq * 8];
      c = mfma16(a, b, c);
    }
    int oc = n * 16 + lq * 4;
    f32x4 bias = *(const f32x4*)&P.d1_b[oc];
    bhalf4 o;
#pragma unroll
    for (int j = 0; j < 4; ++j) o[j] = (bhalf)fmaxf(c[j] + bias[j], 0.f);
    *(bhalf4*)&h1[(m * 16 + l15) * 136 + oc] = o;
  }
  __syncthreads();  // D

  // ---- d2: 2 independent jobs/wave -> h2 (f32) ----
#pragma unroll
  for (int m = 0; m < 2; ++m) {
    int n = wave;
    f32x4 c = {0.f, 0.f, 0.f, 0.f};
#pragma unroll
    for (int ks = 0; ks < 4; ++ks) {
      bhalf8 a = *(const bhalf8*)&P.w_d2[(n * 16 + l15) * 128 + ks * 32 + lq * 8];
      bhalf8 b = *(const bhalf8*)&h1[(m * 16 + l15) * 136 + ks * 32 + lq * 8];
      c = mfma16(a, b, c);
    }
    int oc = n * 16 + lq * 4;
    f32x4 bias = *(const f32x4*)&P.d2_b[oc];
    f32x4 o;
#pragma unroll
    for (int j = 0; j < 4; ++j) o[j] = fmaxf(c[j] + bias[j], 0.f);
    *(f32x4*)&h2[(m * 16 + l15) * 140 + oc] = o;
  }
  __syncthreads();  // E

  // ---- heads: 8 lanes/sample (32 samples x 8 outs = 256 threads) ----
  if (tid < 256) {
    int s = tid >> 3, o = tid & 7;
    const float* wrow = (o < 7) ? &P.pi_w[o * 128] : P.v_w;
    const float* hrow = &h2[s * 140];
    float acc = (o < 7) ? P.pi_b[o] : P.v_b[0];
#pragma unroll
    for (int k = 0; k < 32; ++k) {
      f32x4 wv = *(const f32x4*)&wrow[k * 4];
      f32x4 hv = *(const f32x4*)&hrow[k * 4];
#pragma unroll
      for (int j = 0; j < 4; ++j) acc += wv[j] * hv[j];
    }
    float xm = (o < 7) ? acc : -1e30f;
#pragma unroll
    for (int m = 1; m < 8; m <<= 1) xm = fmaxf(xm, __shfl_xor(xm, m));
    float e = (o < 7) ? __expf(acc - xm) : 0.f;
    float se = e;
#pragma unroll
    for (int m = 1; m < 8; m <<= 1) se += __shfl_xor(se, m);
    if (o < 7) P.out[(size_t)(s0 + s) * 7 + o] = e / se;
    else       P.out[917504 + s0 + s] = acc;  // 131072*7
  }
}

// ---------------- launch ----------------
extern "C" void kernel_launch(void* const* d_in, const int* in_sizes, int n_in,
                              void* d_out, int out_size, void* d_ws, size_t ws_size,
                              hipStream_t stream) {
  (void)in_sizes; (void)n_in; (void)out_size; (void)ws_size;
  const float* const* in = (const float* const*)d_in;
  bhalf* wbf = (bhalf*)d_ws;

  PrepArgs pa;
  const int srcIdx[10] = {5, 9, 11, 15, 21, 25, 27, 31, 35, 37};
  const int lens[10] = {1024, 1024, 1024, 28672, 1024, 1024, 1024, 8192, 49152, 16384};
  const int dsts[10] = {4096, 5120, 6144, 7168, 39936, 40960, 41984, 43008, 55296, 104448};
  for (int i = 0; i < 10; ++i) { pa.src[i] = in[srcIdx[i]]; pa.len[i] = lens[i]; pa.dstOff[i] = dsts[i]; }
  pa.dst = wbf;
  hipLaunchKernelGGL(prep_convert, dim3(424), dim3(256), 0, stream, pa);

  EffArgs ea;
  ea.p_qkv_w = in[3]; ea.p_in_w = in[1]; ea.p_in_b = in[2]; ea.p_qkv_b = in[4]; ea.p_o_b = in[6];
  ea.s_qkv_w = in[19]; ea.s_in_w = in[17]; ea.s_in_b = in[18]; ea.s_qkv_b = in[20]; ea.s_o_b = in[22];
  ea.e_w = in[33]; ea.e_b = in[34];
  ea.dst = wbf;
  hipLaunchKernelGGL(prep_eff, dim3(1), dim3(384), 0, stream, ea);

  Ptrs P;
  P.state = in[0];
  P.p_g1 = in[7];  P.p_b1 = in[8];  P.p_f1b = in[10]; P.p_f2b = in[12];
  P.p_g2 = in[13]; P.p_b2 = in[14]; P.p_out_b = in[16];
  P.s_g1 = in[23]; P.s_b1 = in[24]; P.s_f1b = in[26]; P.s_f2b = in[28];
  P.s_g2 = in[29]; P.s_b2 = in[30]; P.s_out_b = in[32];
  P.d1_b = in[36]; P.d2_b = in[38];
  P.pi_w = in[39]; P.pi_b = in[40]; P.v_w = in[41]; P.v_b = in[42];
  P.A_qp = wbf;          P.A_xp = wbf + 3072;   P.w_o = wbf + 4096;
  P.w_f1 = wbf + 5120;   P.w_f2 = wbf + 6144;   P.w_out = wbf + 7168;
  P.A_qs = wbf + 35840;  P.A_xs = wbf + 38912;  P.w_o2 = wbf + 39936;
  P.w_f12 = wbf + 40960; P.w_f22 = wbf + 41984; P.w_out2 = wbf + 43008;
  P.A_e = wbf + 51200;   P.w_d1 = wbf + 55296;  P.w_d2 = wbf + 104448;
  P.out = (float*)d_out;

  hipLaunchKernelGGL(aac_main, dim3(4096), dim3(512), 0, stream, P);  // 131072/32 blocks
}

// Round 18
// 277.631 us; speedup vs baseline: 1.1210x; 1.1210x over previous
//
#include <hip/hip_runtime.h>

// AttentionActorCritic fused forward, MI355X (gfx950).
// Round 18: zero cross-barrier register state. X' is RECOMPUTED inside
// enc_tile after barrier A (bf fragment rebuilt from L1-hot state, 2 MFMAs
// moved from phase1) instead of held in regs across the barrier (r12-r16
// spilled: 183MB scratch; r17's no-spill VGPR=84 halved occupancy).
// phase1 = QKV only. (512,4), 2 blocks/CU, fixed swizzle, 5 barriers.

typedef __bf16 bhalf;
typedef __bf16 bhalf4 __attribute__((ext_vector_type(4)));
typedef __bf16 bhalf8 __attribute__((ext_vector_type(8)));
typedef float f32x4 __attribute__((ext_vector_type(4)));
typedef float f32x2 __attribute__((ext_vector_type(2)));

#define DEV static __device__ __forceinline__

DEV f32x4 mfma16(bhalf8 a, bhalf8 b, f32x4 c) {
  return __builtin_amdgcn_mfma_f32_16x16x32_bf16(a, b, c, 0, 0, 0);
}

// s_x swizzle: row stride 32 elems (64B = 16 banks). XOR 16B slot with
// (row>>1)&3 so the 8 rows sharing a bank-base spread over all 4 slots.
DEV int sxo(int row, int col) { return row * 32 + (col ^ (((row >> 1) & 3) << 3)); }

// ---------------- pointer bundle ----------------
struct Ptrs {
  const float* state;
  const float *p_g1, *p_b1, *p_f1b, *p_f2b, *p_g2, *p_b2, *p_out_b;
  const float *s_g1, *s_b1, *s_f1b, *s_f2b, *s_g2, *s_b2, *s_out_b;
  const float *d1_b, *d2_b, *pi_w, *pi_b, *v_w, *v_b;
  const bhalf *A_qp, *A_xp, *w_o, *w_f1, *w_f2, *w_out;
  const bhalf *A_qs, *A_xs, *w_o2, *w_f12, *w_f22, *w_out2;
  const bhalf *A_e, *w_d1, *w_d2;
  float* out;
};

// ---------------- prep: fp32 -> bf16 conversions ----------------
struct PrepArgs {
  const float* src[10];
  int len[10];
  int dstOff[10];
  bhalf* dst;
};

__global__ void prep_convert(PrepArgs a) {
  int idx = blockIdx.x * blockDim.x + threadIdx.x;
  int off = 0;
#pragma unroll
  for (int i = 0; i < 10; ++i) {
    int n = a.len[i];
    if (idx >= off && idx < off + n) a.dst[a.dstOff[i] + idx - off] = (bhalf)a.src[i][idx - off];
    off += n;
  }
}

// ---------------- prep: effective (folded) weight matrices ----------------
struct EffArgs {
  const float *p_qkv_w, *p_in_w, *p_in_b, *p_qkv_b, *p_o_b;
  const float *s_qkv_w, *s_in_w, *s_in_b, *s_qkv_b, *s_o_b;
  const float *e_w, *e_b;
  bhalf* dst;
};

__global__ void prep_eff(EffArgs a) {
  int tid = threadIdx.x;
  if (tid < 96) {  // A_qp row o
    const float* wq = a.p_qkv_w + tid * 32;
    float w0 = 0.f, w1 = 0.f, be = 0.f;
    for (int e = 0; e < 32; ++e) {
      w0 += wq[e] * a.p_in_w[e * 2];
      w1 += wq[e] * a.p_in_w[e * 2 + 1];
      be += wq[e] * a.p_in_b[e];
    }
    be += a.p_qkv_b[tid];
    bhalf* d = a.dst + tid * 32;
    for (int k = 0; k < 32; ++k) d[k] = (bhalf)0.f;
    d[0] = (bhalf)w0; d[1] = (bhalf)w1; d[2] = (bhalf)be;
  } else if (tid < 192) {  // A_qs row o
    int o = tid - 96;
    const float* wq = a.s_qkv_w + o * 32;
    float wf[4] = {0.f, 0.f, 0.f, 0.f}, be = 0.f;
    for (int e = 0; e < 32; ++e) {
      for (int f = 0; f < 4; ++f) wf[f] += wq[e] * a.s_in_w[e * 4 + f];
      be += wq[e] * a.s_in_b[e];
    }
    be += a.s_qkv_b[o];
    bhalf* d = a.dst + 35840 + o * 32;
    for (int k = 0; k < 32; ++k) d[k] = (bhalf)0.f;
    for (int f = 0; f < 4; ++f) d[f] = (bhalf)wf[f];
    d[4] = (bhalf)be;
  } else if (tid < 224) {  // A_xp row e
    int e = tid - 192;
    bhalf* d = a.dst + 3072 + e * 32;
    for (int k = 0; k < 32; ++k) d[k] = (bhalf)0.f;
    d[0] = (bhalf)a.p_in_w[e * 2];
    d[1] = (bhalf)a.p_in_w[e * 2 + 1];
    d[2] = (bhalf)(a.p_in_b[e] + a.p_o_b[e]);
  } else if (tid < 256) {  // A_xs row e
    int e = tid - 224;
    bhalf* d = a.dst + 38912 + e * 32;
    for (int k = 0; k < 32; ++k) d[k] = (bhalf)0.f;
    for (int f = 0; f < 4; ++f) d[f] = (bhalf)a.s_in_w[e * 4 + f];
    d[4] = (bhalf)(a.s_in_b[e] + a.s_o_b[e]);
  } else if (tid < 384) {  // A_e row o
    int o = tid - 256;
    bhalf* d = a.dst + 51200 + o * 32;
    for (int k = 0; k < 32; ++k) d[k] = (bhalf)0.f;
    for (int k = 0; k < 8; ++k) d[k] = (bhalf)a.e_w[o * 8 + k];
    d[8] = (bhalf)a.e_b[o];
  }
}

// ---------------- B-fragment build for tile (state from global/L1) ----------------
DEV bhalf8 build_bf(const Ptrs& P, int tile, int s0, int l15, int lq) {
  bhalf8 bf;
#pragma unroll
  for (int k = 0; k < 8; ++k) bf[k] = (bhalf)0.f;
  if (lq == 0) {
    int s = (tile & 1) * 16 + l15;
    const float* st = &P.state[(size_t)(s0 + s) * 30];
    if (tile < 14) {
      int t = tile >> 1;
      f32x2 v = *(const f32x2*)(st + 2 * t);
      bf[0] = (bhalf)v[0]; bf[1] = (bhalf)v[1]; bf[2] = (bhalf)1.0f;
    } else {
      int ts = (tile - 14) >> 1;
      f32x2 v0 = *(const f32x2*)(st + 14 + 4 * ts);
      f32x2 v1 = *(const f32x2*)(st + 16 + 4 * ts);
      bf[0] = (bhalf)v0[0]; bf[1] = (bhalf)v0[1];
      bf[2] = (bhalf)v1[0]; bf[3] = (bhalf)v1[1];
      bf[4] = (bhalf)1.0f;
    }
  }
  return bf;
}

// ---------------- phase-1 tile: QKV only (6 MFMAs -> LDS) ----------------
DEV void p1_tile(const Ptrs& P, bhalf* s_q, int tile, int s0, int l15, int lq) {
  bhalf8 bf = build_bf(P, tile, s0, l15, lq);
  const bhalf* Aq = (tile >= 14) ? P.A_qs : P.A_qp;
  const int row = tile * 16 + l15;
#pragma unroll
  for (int n = 0; n < 6; ++n) {
    f32x4 c = {0.f, 0.f, 0.f, 0.f};
    c = mfma16(*(const bhalf8*)&Aq[(n * 16 + l15) * 32 + lq * 8], bf, c);
    bhalf4 o;
#pragma unroll
    for (int j = 0; j < 4; ++j) o[j] = (bhalf)c[j];
    *(bhalf4*)&s_q[row * 104 + n * 16 + lq * 4] = o;
  }
}

// ---------------- attention: reg output, qkv stride 104, token stride 32 rows ----------------
template <int T>
DEV bhalf8 attn_head(const bhalf* qkv, int rowbase, int a, int s, int h) {
  const bhalf* base = &qkv[(rowbase + s) * 104 + h * 8];
  const int rstep = 32 * 104;
  bhalf8 kf[T];
#pragma unroll
  for (int b = 0; b < T; ++b) kf[b] = *(const bhalf8*)(base + b * rstep + 32);
  bhalf8 qv = *(const bhalf8*)(base + a * rstep);
  float q[8];
#pragma unroll
  for (int i = 0; i < 8; ++i) q[i] = (float)qv[i];
  float sc[T];
  float mx = -1e30f;
#pragma unroll
  for (int b = 0; b < T; ++b) {
    float d = 0.f;
#pragma unroll
    for (int i = 0; i < 8; ++i) d += q[i] * (float)kf[b][i];
    d *= 0.35355339059327378f;  // 1/sqrt(8)
    sc[b] = d;
    mx = fmaxf(mx, d);
  }
  bhalf8 vf[T];
#pragma unroll
  for (int b = 0; b < T; ++b) vf[b] = *(const bhalf8*)(base + b * rstep + 64);
  float sum = 0.f;
#pragma unroll
  for (int b = 0; b < T; ++b) { sc[b] = __expf(sc[b] - mx); sum += sc[b]; }
  float inv = 1.f / sum;
  float o[8] = {0.f, 0.f, 0.f, 0.f, 0.f, 0.f, 0.f, 0.f};
#pragma unroll
  for (int b = 0; b < T; ++b) {
    float w = sc[b] * inv;
#pragma unroll
    for (int i = 0; i < 8; ++i) o[i] += w * (float)vf[b][i];
  }
  bhalf8 ov;
#pragma unroll
  for (int i = 0; i < 8; ++i) ov[i] = (bhalf)o[i];
  return ov;
}

// ---------------- fused encoder tile-chain (X' recomputed here) ----------------
template <int T>
DEV void enc_tile(const Ptrs& P, const bhalf* s_q, bhalf* s_x, int tile, int s0,
                  int l15, int lq,
                  const bhalf* wo, const bhalf* wf1, const bhalf* wf2,
                  const float* g1, const float* b1, const float* f1b,
                  const float* f2b, const float* g2, const float* b2) {
  // recompute X' (= in-linear + o_b) from folded A_x; bf rebuild is L1-hot
  bhalf8 bf = build_bf(P, tile, s0, l15, lq);
  const bhalf* Ax = (T == 7) ? P.A_xp : P.A_xs;
  f32x4 c0 = {0.f, 0.f, 0.f, 0.f}, c1 = {0.f, 0.f, 0.f, 0.f};
  c0 = mfma16(*(const bhalf8*)&Ax[l15 * 32 + lq * 8], bf, c0);
  c1 = mfma16(*(const bhalf8*)&Ax[(16 + l15) * 32 + lq * 8], bf, c1);
  // attention (overlaps with X' MFMAs in the pipe)
  const int rowbase = (T == 7) ? 0 : 224;
  const int a = (T == 7) ? (tile >> 1) : ((tile - 14) >> 1);
  const int s = (tile & 1) * 16 + l15;
  bhalf8 ov = attn_head<T>(s_q, rowbase, a, s, lq);
  const int row = tile * 16 + l15;
  // o-proj accumulates onto X'
  c0 = mfma16(*(const bhalf8*)&wo[l15 * 32 + lq * 8], ov, c0);
  c1 = mfma16(*(const bhalf8*)&wo[(16 + l15) * 32 + lq * 8], ov, c1);
  // LN1 in-register
  float sum = 0.f, ss = 0.f;
#pragma unroll
  for (int j = 0; j < 4; ++j) { sum += c0[j] + c1[j]; ss += c0[j] * c0[j] + c1[j] * c1[j]; }
  sum += __shfl_xor(sum, 16); sum += __shfl_xor(sum, 32);
  ss += __shfl_xor(ss, 16); ss += __shfl_xor(ss, 32);
  float mu = sum * 0.03125f;
  float rs = rsqrtf(ss * 0.03125f - mu * mu + 1e-5f);
  f32x4 gg0 = *(const f32x4*)&g1[lq * 4], gg1 = *(const f32x4*)&g1[16 + lq * 4];
  f32x4 hb0 = *(const f32x4*)&b1[lq * 4], hb1 = *(const f32x4*)&b1[16 + lq * 4];
  float xn[8];
#pragma unroll
  for (int j = 0; j < 4; ++j) {
    xn[j] = (c0[j] - mu) * rs * gg0[j] + hb0[j];
    xn[4 + j] = (c1[j] - mu) * rs * gg1[j] + hb1[j];
  }
  bhalf4 p0, p1;
#pragma unroll
  for (int j = 0; j < 4; ++j) { p0[j] = (bhalf)xn[j]; p1[j] = (bhalf)xn[4 + j]; }
  *(bhalf4*)&s_x[sxo(row, lq * 4)] = p0;
  *(bhalf4*)&s_x[sxo(row, 16 + lq * 4)] = p1;
  bhalf8 bfr = *(const bhalf8*)&s_x[sxo(row, lq * 8)];
  // FF1 + relu (bounce via s_x; residual xn stays in regs)
  c0 = f32x4{0.f, 0.f, 0.f, 0.f};
  c1 = f32x4{0.f, 0.f, 0.f, 0.f};
  c0 = mfma16(*(const bhalf8*)&wf1[l15 * 32 + lq * 8], bfr, c0);
  c1 = mfma16(*(const bhalf8*)&wf1[(16 + l15) * 32 + lq * 8], bfr, c1);
  f32x4 fb0 = *(const f32x4*)&f1b[lq * 4], fb1 = *(const f32x4*)&f1b[16 + lq * 4];
#pragma unroll
  for (int j = 0; j < 4; ++j) {
    p0[j] = (bhalf)fmaxf(c0[j] + fb0[j], 0.f);
    p1[j] = (bhalf)fmaxf(c1[j] + fb1[j], 0.f);
  }
  *(bhalf4*)&s_x[sxo(row, lq * 4)] = p0;
  *(bhalf4*)&s_x[sxo(row, 16 + lq * 4)] = p1;
  bfr = *(const bhalf8*)&s_x[sxo(row, lq * 8)];
  // FF2 with C-init = xn + f2b (residual + bias), then LN2 -> s_x
  f32x4 f20 = *(const f32x4*)&f2b[lq * 4], f21 = *(const f32x4*)&f2b[16 + lq * 4];
#pragma unroll
  for (int j = 0; j < 4; ++j) { c0[j] = xn[j] + f20[j]; c1[j] = xn[4 + j] + f21[j]; }
  c0 = mfma16(*(const bhalf8*)&wf2[l15 * 32 + lq * 8], bfr, c0);
  c1 = mfma16(*(const bhalf8*)&wf2[(16 + l15) * 32 + lq * 8], bfr, c1);
  sum = 0.f; ss = 0.f;
#pragma unroll
  for (int j = 0; j < 4; ++j) { sum += c0[j] + c1[j]; ss += c0[j] * c0[j] + c1[j] * c1[j]; }
  sum += __shfl_xor(sum, 16); sum += __shfl_xor(sum, 32);
  ss += __shfl_xor(ss, 16); ss += __shfl_xor(ss, 32);
  mu = sum * 0.03125f;
  rs = rsqrtf(ss * 0.03125f - mu * mu + 1e-5f);
  f32x4 g20 = *(const f32x4*)&g2[lq * 4], g21 = *(const f32x4*)&g2[16 + lq * 4];
  f32x4 b20 = *(const f32x4*)&b2[lq * 4], b21 = *(const f32x4*)&b2[16 + lq * 4];
#pragma unroll
  for (int j = 0; j < 4; ++j) {
    p0[j] = (bhalf)((c0[j] - mu) * rs * g20[j] + b20[j]);
    p1[j] = (bhalf)((c1[j] - mu) * rs * g21[j] + b21[j]);
  }
  *(bhalf4*)&s_x[sxo(row, lq * 4)] = p0;
  *(bhalf4*)&s_x[sxo(row, 16 + lq * 4)] = p1;
}

// ---------------- main fused kernel: 32 samples/block ----------------
__launch_bounds__(512, 4)
__global__ void aac_main(Ptrs P) {
  // 18432 + 59904 = 78336 B -> 2 blocks/CU
  __shared__ __align__(16) bhalf s_x[288 * 32];   // LN2 out + chain bounces (swizzled)
  __shared__ __align__(16) bhalf s_q[288 * 104];  // qkv; aliases xcat/h1/h2

  bhalf* xcat = s_q;                   // [32][408] elems 0..13055
  bhalf* h1 = s_q + 13056;             // [32][136]
  float* h2 = (float*)(s_q + 17408);   // [32][140] f32

  const int tid = threadIdx.x;
  const int wave = tid >> 6, lane = tid & 63;
  const int l15 = lane & 15, lq = lane >> 4;
  const int s0 = blockIdx.x * 32;

  // ---- phase 1: QKV only; nothing held across barrier A ----
  p1_tile(P, s_q, wave, s0, l15, lq);
  p1_tile(P, s_q, wave + 8, s0, l15, lq);
  if (wave < 2) p1_tile(P, s_q, 16 + wave, s0, l15, lq);
  __syncthreads();  // A

  // ---- fused encoder: 18 tile-chains, 2-3 independent chains per wave ----
  enc_tile<7>(P, s_q, s_x, wave, s0, l15, lq,
              P.w_o, P.w_f1, P.w_f2, P.p_g1, P.p_b1, P.p_f1b, P.p_f2b, P.p_g2, P.p_b2);
  if (wave < 6) {
    enc_tile<7>(P, s_q, s_x, wave + 8, s0, l15, lq,
                P.w_o, P.w_f1, P.w_f2, P.p_g1, P.p_b1, P.p_f1b, P.p_f2b, P.p_g2, P.p_b2);
  } else {
    enc_tile<2>(P, s_q, s_x, wave + 8, s0, l15, lq,
                P.w_o2, P.w_f12, P.w_f22, P.s_g1, P.s_b1, P.s_f1b, P.s_f2b, P.s_g2, P.s_b2);
  }
  if (wave < 2) {
    enc_tile<2>(P, s_q, s_x, 16 + wave, s0, l15, lq,
                P.w_o2, P.w_f12, P.w_f22, P.s_g1, P.s_b1, P.s_f1b, P.s_f2b, P.s_g2, P.s_b2);
  }
  __syncthreads();  // B

  // ---- out_gemm + st_emb -> xcat (48 jobs, 6/wave) ----
#pragma unroll
  for (int k = 0; k < 2; ++k) {  // power out
    int f = wave + 8 * k;
    int n = f >> 1, m = f & 1;
    f32x4 c = {0.f, 0.f, 0.f, 0.f};
#pragma unroll
    for (int t = 0; t < 7; ++t) {
      bhalf8 a = *(const bhalf8*)&P.w_out[(n * 16 + l15) * 224 + t * 32 + lq * 8];
      bhalf8 b = *(const bhalf8*)&s_x[sxo(t * 32 + m * 16 + l15, lq * 8)];
      c = mfma16(a, b, c);
    }
    int oc = n * 16 + lq * 4;
    f32x4 bias = *(const f32x4*)&P.p_out_b[oc];
    bhalf4 o;
#pragma unroll
    for (int j = 0; j < 4; ++j) o[j] = (bhalf)fmaxf(c[j] + bias[j], 0.f);
    *(bhalf4*)&xcat[(m * 16 + l15) * 408 + oc] = o;
  }
#pragma unroll
  for (int k = 0; k < 2; ++k) {  // sword out
    int g = wave + 8 * k;
    int n = g >> 1, m = g & 1;
    f32x4 c = {0.f, 0.f, 0.f, 0.f};
#pragma unroll
    for (int t = 0; t < 2; ++t) {
      bhalf8 a = *(const bhalf8*)&P.w_out2[(n * 16 + l15) * 64 + t * 32 + lq * 8];
      bhalf8 b = *(const bhalf8*)&s_x[sxo(224 + t * 32 + m * 16 + l15, lq * 8)];
      c = mfma16(a, b, c);
    }
    int oc = n * 16 + lq * 4;
    f32x4 bias = *(const f32x4*)&P.s_out_b[oc];
    bhalf4 o;
#pragma unroll
    for (int j = 0; j < 4; ++j) o[j] = (bhalf)fmaxf(c[j] + bias[j], 0.f);
    *(bhalf4*)&xcat[(m * 16 + l15) * 408 + 128 + oc] = o;
  }
#pragma unroll
  for (int k = 0; k < 2; ++k) {  // st_emb
    int g = wave + 8 * k;
    int n = g >> 1, m = g & 1;
    int s = m * 16 + l15;
    bhalf8 bf;
#pragma unroll
    for (int kk = 0; kk < 8; ++kk) bf[kk] = (bhalf)0.f;
    if (lq == 0) {
      const float* st = &P.state[(size_t)(s0 + s) * 30 + 22];
#pragma unroll
      for (int kk = 0; kk < 4; ++kk) {
        f32x2 v = *(const f32x2*)(st + 2 * kk);
        bf[2 * kk] = (bhalf)v[0];
        bf[2 * kk + 1] = (bhalf)v[1];
      }
    } else if (lq == 1) {
      bf[0] = (bhalf)1.0f;
    }
    bhalf8 a = *(const bhalf8*)&P.A_e[(n * 16 + l15) * 32 + lq * 8];
    f32x4 c = {0.f, 0.f, 0.f, 0.f};
    c = mfma16(a, bf, c);
    bhalf4 o;
#pragma unroll
    for (int j = 0; j < 4; ++j) o[j] = (bhalf)fmaxf(c[j], 0.f);
    *(bhalf4*)&xcat[s * 408 + 256 + n * 16 + lq * 4] = o;
  }
  __syncthreads();  // C

  // ---- d1: 2 independent jobs/wave (m=0,1; n=wave) -> h1 ----
#pragma unroll
  for (int m = 0; m < 2; ++m) {
    int n = wave;
    f32x4 c = {0.f, 0.f, 0.f, 0.f};
#pragma unroll
    for (int ks = 0; ks < 12; ++ks) {
      bhalf8 a = *(const bhalf8*)&P.w_d1[(n * 16 + l15) * 384 + ks * 32 + lq * 8];
      bhalf8 b = *(const bhalf8*)&xcat[(m * 16 + l15) * 408 + ks * 32 + lq * 8];
      c = mfma16(a, b, c);
    }
    int oc = n * 16 + lq * 4;
    f32x4 bias = *(const f32x4*)&P.d1_b[oc];
    bhalf4 o;
#pragma unroll
    for (int j = 0; j < 4; ++j) o[j] = (bhalf)fmaxf(c[j] + bias[j], 0.f);
    *(bhalf4*)&h1[(m * 16 + l15) * 136 + oc] = o;
  }
  __syncthreads();  // D

  // ---- d2: 2 independent jobs/wave -> h2 (f32) ----
#pragma unroll
  for (int m = 0; m < 2; ++m) {
    int n = wave;
    f32x4 c = {0.f, 0.f, 0.f, 0.f};
#pragma unroll
    for (int ks = 0; ks < 4; ++ks) {
      bhalf8 a = *(const bhalf8*)&P.w_d2[(n * 16 + l15) * 128 + ks * 32 + lq * 8];
      bhalf8 b = *(const bhalf8*)&h1[(m * 16 + l15) * 136 + ks * 32 + lq * 8];
      c = mfma16(a, b, c);
    }
    int oc = n * 16 + lq * 4;
    f32x4 bias = *(const f32x4*)&P.d2_b[oc];
    f32x4 o;
#pragma unroll
    for (int j = 0; j < 4; ++j) o[j] = fmaxf(c[j] + bias[j], 0.f);
    *(f32x4*)&h2[(m * 16 + l15) * 140 + oc] = o;
  }
  __syncthreads();  // E

  // ---- heads: 8 lanes/sample (32 samples x 8 outs = 256 threads) ----
  if (tid < 256) {
    int s = tid >> 3, o = tid & 7;
    const float* wrow = (o < 7) ? &P.pi_w[o * 128] : P.v_w;
    const float* hrow = &h2[s * 140];
    float acc = (o < 7) ? P.pi_b[o] : P.v_b[0];
#pragma unroll
    for (int k = 0; k < 32; ++k) {
      f32x4 wv = *(const f32x4*)&wrow[k * 4];
      f32x4 hv = *(const f32x4*)&hrow[k * 4];
#pragma unroll
      for (int j = 0; j < 4; ++j) acc += wv[j] * hv[j];
    }
    float xm = (o < 7) ? acc : -1e30f;
#pragma unroll
    for (int m = 1; m < 8; m <<= 1) xm = fmaxf(xm, __shfl_xor(xm, m));
    float e = (o < 7) ? __expf(acc - xm) : 0.f;
    float se = e;
#pragma unroll
    for (int m = 1; m < 8; m <<= 1) se += __shfl_xor(se, m);
    if (o < 7) P.out[(size_t)(s0 + s) * 7 + o] = e / se;
    else       P.out[917504 + s0 + s] = acc;  // 131072*7
  }
}

// ---------------- launch ----------------
extern "C" void kernel_launch(void* const* d_in, const int* in_sizes, int n_in,
                              void* d_out, int out_size, void* d_ws, size_t ws_size,
                              hipStream_t stream) {
  (void)in_sizes; (void)n_in; (void)out_size; (void)ws_size;
  const float* const* in = (const float* const*)d_in;
  bhalf* wbf = (bhalf*)d_ws;

  PrepArgs pa;
  const int srcIdx[10] = {5, 9, 11, 15, 21, 25, 27, 31, 35, 37};
  const int lens[10] = {1024, 1024, 1024, 28672, 1024, 1024, 1024, 8192, 49152, 16384};
  const int dsts[10] = {4096, 5120, 6144, 7168, 39936, 40960, 41984, 43008, 55296, 104448};
  for (int i = 0; i < 10; ++i) { pa.src[i] = in[srcIdx[i]]; pa.len[i] = lens[i]; pa.dstOff[i] = dsts[i]; }
  pa.dst = wbf;
  hipLaunchKernelGGL(prep_convert, dim3(424), dim3(256), 0, stream, pa);

  EffArgs ea;
  ea.p_qkv_w = in[3]; ea.p_in_w = in[1]; ea.p_in_b = in[2]; ea.p_qkv_b = in[4]; ea.p_o_b = in[6];
  ea.s_qkv_w = in[19]; ea.s_in_w = in[17]; ea.s_in_b = in[18]; ea.s_qkv_b = in[20]; ea.s_o_b = in[22];
  ea.e_w = in[33]; ea.e_b = in[34];
  ea.dst = wbf;
  hipLaunchKernelGGL(prep_eff, dim3(1), dim3(384), 0, stream, ea);

  Ptrs P;
  P.state = in[0];
  P.p_g1 = in[7];  P.p_b1 = in[8];  P.p_f1b = in[10]; P.p_f2b = in[12];
  P.p_g2 = in[13]; P.p_b2 = in[14]; P.p_out_b = in[16];
  P.s_g1 = in[23]; P.s_b1 = in[24]; P.s_f1b = in[26]; P.s_f2b = in[28];
  P.s_g2 = in[29]; P.s_b2 = in[30]; P.s_out_b = in[32];
  P.d1_b = in[36]; P.d2_b = in[38];
  P.pi_w = in[39]; P.pi_b = in[40]; P.v_w = in[41]; P.v_b = in[42];
  P.A_qp = wbf;          P.A_xp = wbf + 3072;   P.w_o = wbf + 4096;
  P.w_f1 = wbf + 5120;   P.w_f2 = wbf + 6144;   P.w_out = wbf + 7168;
  P.A_qs = wbf + 35840;  P.A_xs = wbf + 38912;  P.w_o2 = wbf + 39936;
  P.w_f12 = wbf + 40960; P.w_f22 = wbf + 41984; P.w_out2 = wbf + 43008;
  P.A_e = wbf + 51200;   P.w_d1 = wbf + 55296;  P.w_d2 = wbf + 104448;
  P.out = (float*)d_out;

  hipLaunchKernelGGL(aac_main, dim3(4096), dim3(512), 0, stream, P);  // 131072/32 blocks
}

// Round 19
// 272.175 us; speedup vs baseline: 1.1435x; 1.0200x over previous
//
#include <hip/hip_runtime.h>

// AttentionActorCritic fused forward, MI355X (gfx950).
// Round 19: r18 + compiler scheduling fences (asm memory clobber) between
// chain calls. At VGPR=64 the compiler interleaved 2-3 enc chains and spilled
// ~32KB/block (WRITE_SIZE 132MB). Fences serialize chain register lifetimes:
// live set per chain ~60 regs < 64 -> no spill. Cross-wave TLP (16 waves/CU)
// provides the overlap instead. Everything else identical to r18.

typedef __bf16 bhalf;
typedef __bf16 bhalf4 __attribute__((ext_vector_type(4)));
typedef __bf16 bhalf8 __attribute__((ext_vector_type(8)));
typedef float f32x4 __attribute__((ext_vector_type(4)));
typedef float f32x2 __attribute__((ext_vector_type(2)));

#define DEV static __device__ __forceinline__

DEV f32x4 mfma16(bhalf8 a, bhalf8 b, f32x4 c) {
  return __builtin_amdgcn_mfma_f32_16x16x32_bf16(a, b, c, 0, 0, 0);
}

DEV void sched_fence() { asm volatile("" ::: "memory"); }

// s_x swizzle: row stride 32 elems (64B = 16 banks). XOR 16B slot with
// (row>>1)&3 so the 8 rows sharing a bank-base spread over all 4 slots.
DEV int sxo(int row, int col) { return row * 32 + (col ^ (((row >> 1) & 3) << 3)); }

// ---------------- pointer bundle ----------------
struct Ptrs {
  const float* state;
  const float *p_g1, *p_b1, *p_f1b, *p_f2b, *p_g2, *p_b2, *p_out_b;
  const float *s_g1, *s_b1, *s_f1b, *s_f2b, *s_g2, *s_b2, *s_out_b;
  const float *d1_b, *d2_b, *pi_w, *pi_b, *v_w, *v_b;
  const bhalf *A_qp, *A_xp, *w_o, *w_f1, *w_f2, *w_out;
  const bhalf *A_qs, *A_xs, *w_o2, *w_f12, *w_f22, *w_out2;
  const bhalf *A_e, *w_d1, *w_d2;
  float* out;
};

// ---------------- prep: fp32 -> bf16 conversions ----------------
struct PrepArgs {
  const float* src[10];
  int len[10];
  int dstOff[10];
  bhalf* dst;
};

__global__ void prep_convert(PrepArgs a) {
  int idx = blockIdx.x * blockDim.x + threadIdx.x;
  int off = 0;
#pragma unroll
  for (int i = 0; i < 10; ++i) {
    int n = a.len[i];
    if (idx >= off && idx < off + n) a.dst[a.dstOff[i] + idx - off] = (bhalf)a.src[i][idx - off];
    off += n;
  }
}

// ---------------- prep: effective (folded) weight matrices ----------------
struct EffArgs {
  const float *p_qkv_w, *p_in_w, *p_in_b, *p_qkv_b, *p_o_b;
  const float *s_qkv_w, *s_in_w, *s_in_b, *s_qkv_b, *s_o_b;
  const float *e_w, *e_b;
  bhalf* dst;
};

__global__ void prep_eff(EffArgs a) {
  int tid = threadIdx.x;
  if (tid < 96) {  // A_qp row o
    const float* wq = a.p_qkv_w + tid * 32;
    float w0 = 0.f, w1 = 0.f, be = 0.f;
    for (int e = 0; e < 32; ++e) {
      w0 += wq[e] * a.p_in_w[e * 2];
      w1 += wq[e] * a.p_in_w[e * 2 + 1];
      be += wq[e] * a.p_in_b[e];
    }
    be += a.p_qkv_b[tid];
    bhalf* d = a.dst + tid * 32;
    for (int k = 0; k < 32; ++k) d[k] = (bhalf)0.f;
    d[0] = (bhalf)w0; d[1] = (bhalf)w1; d[2] = (bhalf)be;
  } else if (tid < 192) {  // A_qs row o
    int o = tid - 96;
    const float* wq = a.s_qkv_w + o * 32;
    float wf[4] = {0.f, 0.f, 0.f, 0.f}, be = 0.f;
    for (int e = 0; e < 32; ++e) {
      for (int f = 0; f < 4; ++f) wf[f] += wq[e] * a.s_in_w[e * 4 + f];
      be += wq[e] * a.s_in_b[e];
    }
    be += a.s_qkv_b[o];
    bhalf* d = a.dst + 35840 + o * 32;
    for (int k = 0; k < 32; ++k) d[k] = (bhalf)0.f;
    for (int f = 0; f < 4; ++f) d[f] = (bhalf)wf[f];
    d[4] = (bhalf)be;
  } else if (tid < 224) {  // A_xp row e
    int e = tid - 192;
    bhalf* d = a.dst + 3072 + e * 32;
    for (int k = 0; k < 32; ++k) d[k] = (bhalf)0.f;
    d[0] = (bhalf)a.p_in_w[e * 2];
    d[1] = (bhalf)a.p_in_w[e * 2 + 1];
    d[2] = (bhalf)(a.p_in_b[e] + a.p_o_b[e]);
  } else if (tid < 256) {  // A_xs row e
    int e = tid - 224;
    bhalf* d = a.dst + 38912 + e * 32;
    for (int k = 0; k < 32; ++k) d[k] = (bhalf)0.f;
    for (int f = 0; f < 4; ++f) d[f] = (bhalf)a.s_in_w[e * 4 + f];
    d[4] = (bhalf)(a.s_in_b[e] + a.s_o_b[e]);
  } else if (tid < 384) {  // A_e row o
    int o = tid - 256;
    bhalf* d = a.dst + 51200 + o * 32;
    for (int k = 0; k < 32; ++k) d[k] = (bhalf)0.f;
    for (int k = 0; k < 8; ++k) d[k] = (bhalf)a.e_w[o * 8 + k];
    d[8] = (bhalf)a.e_b[o];
  }
}

// ---------------- B-fragment build for tile (state from global/L1) ----------------
DEV bhalf8 build_bf(const Ptrs& P, int tile, int s0, int l15, int lq) {
  bhalf8 bf;
#pragma unroll
  for (int k = 0; k < 8; ++k) bf[k] = (bhalf)0.f;
  if (lq == 0) {
    int s = (tile & 1) * 16 + l15;
    const float* st = &P.state[(size_t)(s0 + s) * 30];
    if (tile < 14) {
      int t = tile >> 1;
      f32x2 v = *(const f32x2*)(st + 2 * t);
      bf[0] = (bhalf)v[0]; bf[1] = (bhalf)v[1]; bf[2] = (bhalf)1.0f;
    } else {
      int ts = (tile - 14) >> 1;
      f32x2 v0 = *(const f32x2*)(st + 14 + 4 * ts);
      f32x2 v1 = *(const f32x2*)(st + 16 + 4 * ts);
      bf[0] = (bhalf)v0[0]; bf[1] = (bhalf)v0[1];
      bf[2] = (bhalf)v1[0]; bf[3] = (bhalf)v1[1];
      bf[4] = (bhalf)1.0f;
    }
  }
  return bf;
}

// ---------------- phase-1 tile: QKV only (6 MFMAs -> LDS) ----------------
DEV void p1_tile(const Ptrs& P, bhalf* s_q, int tile, int s0, int l15, int lq) {
  bhalf8 bf = build_bf(P, tile, s0, l15, lq);
  const bhalf* Aq = (tile >= 14) ? P.A_qs : P.A_qp;
  const int row = tile * 16 + l15;
#pragma unroll
  for (int n = 0; n < 6; ++n) {
    f32x4 c = {0.f, 0.f, 0.f, 0.f};
    c = mfma16(*(const bhalf8*)&Aq[(n * 16 + l15) * 32 + lq * 8], bf, c);
    bhalf4 o;
#pragma unroll
    for (int j = 0; j < 4; ++j) o[j] = (bhalf)c[j];
    *(bhalf4*)&s_q[row * 104 + n * 16 + lq * 4] = o;
  }
}

// ---------------- attention: reg output, qkv stride 104, token stride 32 rows ----------------
template <int T>
DEV bhalf8 attn_head(const bhalf* qkv, int rowbase, int a, int s, int h) {
  const bhalf* base = &qkv[(rowbase + s) * 104 + h * 8];
  const int rstep = 32 * 104;
  bhalf8 kf[T];
#pragma unroll
  for (int b = 0; b < T; ++b) kf[b] = *(const bhalf8*)(base + b * rstep + 32);
  bhalf8 qv = *(const bhalf8*)(base + a * rstep);
  float q[8];
#pragma unroll
  for (int i = 0; i < 8; ++i) q[i] = (float)qv[i];
  float sc[T];
  float mx = -1e30f;
#pragma unroll
  for (int b = 0; b < T; ++b) {
    float d = 0.f;
#pragma unroll
    for (int i = 0; i < 8; ++i) d += q[i] * (float)kf[b][i];
    d *= 0.35355339059327378f;  // 1/sqrt(8)
    sc[b] = d;
    mx = fmaxf(mx, d);
  }
  bhalf8 vf[T];
#pragma unroll
  for (int b = 0; b < T; ++b) vf[b] = *(const bhalf8*)(base + b * rstep + 64);
  float sum = 0.f;
#pragma unroll
  for (int b = 0; b < T; ++b) { sc[b] = __expf(sc[b] - mx); sum += sc[b]; }
  float inv = 1.f / sum;
  float o[8] = {0.f, 0.f, 0.f, 0.f, 0.f, 0.f, 0.f, 0.f};
#pragma unroll
  for (int b = 0; b < T; ++b) {
    float w = sc[b] * inv;
#pragma unroll
    for (int i = 0; i < 8; ++i) o[i] += w * (float)vf[b][i];
  }
  bhalf8 ov;
#pragma unroll
  for (int i = 0; i < 8; ++i) ov[i] = (bhalf)o[i];
  return ov;
}

// ---------------- fused encoder tile-chain (X' recomputed here) ----------------
template <int T>
DEV void enc_tile(const Ptrs& P, const bhalf* s_q, bhalf* s_x, int tile, int s0,
                  int l15, int lq,
                  const bhalf* wo, const bhalf* wf1, const bhalf* wf2,
                  const float* g1, const float* b1, const float* f1b,
                  const float* f2b, const float* g2, const float* b2) {
  // recompute X' (= in-linear + o_b) from folded A_x; bf rebuild is L1-hot
  bhalf8 bf = build_bf(P, tile, s0, l15, lq);
  const bhalf* Ax = (T == 7) ? P.A_xp : P.A_xs;
  f32x4 c0 = {0.f, 0.f, 0.f, 0.f}, c1 = {0.f, 0.f, 0.f, 0.f};
  c0 = mfma16(*(const bhalf8*)&Ax[l15 * 32 + lq * 8], bf, c0);
  c1 = mfma16(*(const bhalf8*)&Ax[(16 + l15) * 32 + lq * 8], bf, c1);
  // attention
  const int rowbase = (T == 7) ? 0 : 224;
  const int a = (T == 7) ? (tile >> 1) : ((tile - 14) >> 1);
  const int s = (tile & 1) * 16 + l15;
  bhalf8 ov = attn_head<T>(s_q, rowbase, a, s, lq);
  const int row = tile * 16 + l15;
  // o-proj accumulates onto X'
  c0 = mfma16(*(const bhalf8*)&wo[l15 * 32 + lq * 8], ov, c0);
  c1 = mfma16(*(const bhalf8*)&wo[(16 + l15) * 32 + lq * 8], ov, c1);
  // LN1 in-register
  float sum = 0.f, ss = 0.f;
#pragma unroll
  for (int j = 0; j < 4; ++j) { sum += c0[j] + c1[j]; ss += c0[j] * c0[j] + c1[j] * c1[j]; }
  sum += __shfl_xor(sum, 16); sum += __shfl_xor(sum, 32);
  ss += __shfl_xor(ss, 16); ss += __shfl_xor(ss, 32);
  float mu = sum * 0.03125f;
  float rs = rsqrtf(ss * 0.03125f - mu * mu + 1e-5f);
  f32x4 gg0 = *(const f32x4*)&g1[lq * 4], gg1 = *(const f32x4*)&g1[16 + lq * 4];
  f32x4 hb0 = *(const f32x4*)&b1[lq * 4], hb1 = *(const f32x4*)&b1[16 + lq * 4];
  float xn[8];
#pragma unroll
  for (int j = 0; j < 4; ++j) {
    xn[j] = (c0[j] - mu) * rs * gg0[j] + hb0[j];
    xn[4 + j] = (c1[j] - mu) * rs * gg1[j] + hb1[j];
  }
  bhalf4 p0, p1;
#pragma unroll
  for (int j = 0; j < 4; ++j) { p0[j] = (bhalf)xn[j]; p1[j] = (bhalf)xn[4 + j]; }
  *(bhalf4*)&s_x[sxo(row, lq * 4)] = p0;
  *(bhalf4*)&s_x[sxo(row, 16 + lq * 4)] = p1;
  bhalf8 bfr = *(const bhalf8*)&s_x[sxo(row, lq * 8)];
  // FF1 + relu (bounce via s_x; residual xn stays in regs)
  c0 = f32x4{0.f, 0.f, 0.f, 0.f};
  c1 = f32x4{0.f, 0.f, 0.f, 0.f};
  c0 = mfma16(*(const bhalf8*)&wf1[l15 * 32 + lq * 8], bfr, c0);
  c1 = mfma16(*(const bhalf8*)&wf1[(16 + l15) * 32 + lq * 8], bfr, c1);
  f32x4 fb0 = *(const f32x4*)&f1b[lq * 4], fb1 = *(const f32x4*)&f1b[16 + lq * 4];
#pragma unroll
  for (int j = 0; j < 4; ++j) {
    p0[j] = (bhalf)fmaxf(c0[j] + fb0[j], 0.f);
    p1[j] = (bhalf)fmaxf(c1[j] + fb1[j], 0.f);
  }
  *(bhalf4*)&s_x[sxo(row, lq * 4)] = p0;
  *(bhalf4*)&s_x[sxo(row, 16 + lq * 4)] = p1;
  bfr = *(const bhalf8*)&s_x[sxo(row, lq * 8)];
  // FF2 with C-init = xn + f2b (residual + bias), then LN2 -> s_x
  f32x4 f20 = *(const f32x4*)&f2b[lq * 4], f21 = *(const f32x4*)&f2b[16 + lq * 4];
#pragma unroll
  for (int j = 0; j < 4; ++j) { c0[j] = xn[j] + f20[j]; c1[j] = xn[4 + j] + f21[j]; }
  c0 = mfma16(*(const bhalf8*)&wf2[l15 * 32 + lq * 8], bfr, c0);
  c1 = mfma16(*(const bhalf8*)&wf2[(16 + l15) * 32 + lq * 8], bfr, c1);
  sum = 0.f; ss = 0.f;
#pragma unroll
  for (int j = 0; j < 4; ++j) { sum += c0[j] + c1[j]; ss += c0[j] * c0[j] + c1[j] * c1[j]; }
  sum += __shfl_xor(sum, 16); sum += __shfl_xor(sum, 32);
  ss += __shfl_xor(ss, 16); ss += __shfl_xor(ss, 32);
  mu = sum * 0.03125f;
  rs = rsqrtf(ss * 0.03125f - mu * mu + 1e-5f);
  f32x4 g20 = *(const f32x4*)&g2[lq * 4], g21 = *(const f32x4*)&g2[16 + lq * 4];
  f32x4 b20 = *(const f32x4*)&b2[lq * 4], b21 = *(const f32x4*)&b2[16 + lq * 4];
#pragma unroll
  for (int j = 0; j < 4; ++j) {
    p0[j] = (bhalf)((c0[j] - mu) * rs * g20[j] + b20[j]);
    p1[j] = (bhalf)((c1[j] - mu) * rs * g21[j] + b21[j]);
  }
  *(bhalf4*)&s_x[sxo(row, lq * 4)] = p0;
  *(bhalf4*)&s_x[sxo(row, 16 + lq * 4)] = p1;
}

// ---------------- main fused kernel: 32 samples/block ----------------
__launch_bounds__(512, 4)
__global__ void aac_main(Ptrs P) {
  // 18432 + 59904 = 78336 B -> 2 blocks/CU
  __shared__ __align__(16) bhalf s_x[288 * 32];   // LN2 out + chain bounces (swizzled)
  __shared__ __align__(16) bhalf s_q[288 * 104];  // qkv; aliases xcat/h1/h2

  bhalf* xcat = s_q;                   // [32][408] elems 0..13055
  bhalf* h1 = s_q + 13056;             // [32][136]
  float* h2 = (float*)(s_q + 17408);   // [32][140] f32

  const int tid = threadIdx.x;
  const int wave = tid >> 6, lane = tid & 63;
  const int l15 = lane & 15, lq = lane >> 4;
  const int s0 = blockIdx.x * 32;

  // ---- phase 1: QKV only; fences keep chains sequential (no spill) ----
  p1_tile(P, s_q, wave, s0, l15, lq);
  sched_fence();
  p1_tile(P, s_q, wave + 8, s0, l15, lq);
  sched_fence();
  if (wave < 2) p1_tile(P, s_q, 16 + wave, s0, l15, lq);
  __syncthreads();  // A

  // ---- fused encoder: 18 tile-chains, sequential per wave (fenced) ----
  enc_tile<7>(P, s_q, s_x, wave, s0, l15, lq,
              P.w_o, P.w_f1, P.w_f2, P.p_g1, P.p_b1, P.p_f1b, P.p_f2b, P.p_g2, P.p_b2);
  sched_fence();
  if (wave < 6) {
    enc_tile<7>(P, s_q, s_x, wave + 8, s0, l15, lq,
                P.w_o, P.w_f1, P.w_f2, P.p_g1, P.p_b1, P.p_f1b, P.p_f2b, P.p_g2, P.p_b2);
  } else {
    enc_tile<2>(P, s_q, s_x, wave + 8, s0, l15, lq,
                P.w_o2, P.w_f12, P.w_f22, P.s_g1, P.s_b1, P.s_f1b, P.s_f2b, P.s_g2, P.s_b2);
  }
  sched_fence();
  if (wave < 2) {
    enc_tile<2>(P, s_q, s_x, 16 + wave, s0, l15, lq,
                P.w_o2, P.w_f12, P.w_f22, P.s_g1, P.s_b1, P.s_f1b, P.s_f2b, P.s_g2, P.s_b2);
  }
  __syncthreads();  // B

  // ---- out_gemm + st_emb -> xcat (48 jobs, 6/wave) ----
#pragma unroll
  for (int k = 0; k < 2; ++k) {  // power out
    int f = wave + 8 * k;
    int n = f >> 1, m = f & 1;
    f32x4 c = {0.f, 0.f, 0.f, 0.f};
#pragma unroll
    for (int t = 0; t < 7; ++t) {
      bhalf8 a = *(const bhalf8*)&P.w_out[(n * 16 + l15) * 224 + t * 32 + lq * 8];
      bhalf8 b = *(const bhalf8*)&s_x[sxo(t * 32 + m * 16 + l15, lq * 8)];
      c = mfma16(a, b, c);
    }
    int oc = n * 16 + lq * 4;
    f32x4 bias = *(const f32x4*)&P.p_out_b[oc];
    bhalf4 o;
#pragma unroll
    for (int j = 0; j < 4; ++j) o[j] = (bhalf)fmaxf(c[j] + bias[j], 0.f);
    *(bhalf4*)&xcat[(m * 16 + l15) * 408 + oc] = o;
  }
#pragma unroll
  for (int k = 0; k < 2; ++k) {  // sword out
    int g = wave + 8 * k;
    int n = g >> 1, m = g & 1;
    f32x4 c = {0.f, 0.f, 0.f, 0.f};
#pragma unroll
    for (int t = 0; t < 2; ++t) {
      bhalf8 a = *(const bhalf8*)&P.w_out2[(n * 16 + l15) * 64 + t * 32 + lq * 8];
      bhalf8 b = *(const bhalf8*)&s_x[sxo(224 + t * 32 + m * 16 + l15, lq * 8)];
      c = mfma16(a, b, c);
    }
    int oc = n * 16 + lq * 4;
    f32x4 bias = *(const f32x4*)&P.s_out_b[oc];
    bhalf4 o;
#pragma unroll
    for (int j = 0; j < 4; ++j) o[j] = (bhalf)fmaxf(c[j] + bias[j], 0.f);
    *(bhalf4*)&xcat[(m * 16 + l15) * 408 + 128 + oc] = o;
  }
#pragma unroll
  for (int k = 0; k < 2; ++k) {  // st_emb
    int g = wave + 8 * k;
    int n = g >> 1, m = g & 1;
    int s = m * 16 + l15;
    bhalf8 bf;
#pragma unroll
    for (int kk = 0; kk < 8; ++kk) bf[kk] = (bhalf)0.f;
    if (lq == 0) {
      const float* st = &P.state[(size_t)(s0 + s) * 30 + 22];
#pragma unroll
      for (int kk = 0; kk < 4; ++kk) {
        f32x2 v = *(const f32x2*)(st + 2 * kk);
        bf[2 * kk] = (bhalf)v[0];
        bf[2 * kk + 1] = (bhalf)v[1];
      }
    } else if (lq == 1) {
      bf[0] = (bhalf)1.0f;
    }
    bhalf8 a = *(const bhalf8*)&P.A_e[(n * 16 + l15) * 32 + lq * 8];
    f32x4 c = {0.f, 0.f, 0.f, 0.f};
    c = mfma16(a, bf, c);
    bhalf4 o;
#pragma unroll
    for (int j = 0; j < 4; ++j) o[j] = (bhalf)fmaxf(c[j], 0.f);
    *(bhalf4*)&xcat[s * 408 + 256 + n * 16 + lq * 4] = o;
  }
  __syncthreads();  // C

  // ---- d1: 2 independent jobs/wave (m=0,1; n=wave) -> h1 ----
#pragma unroll
  for (int m = 0; m < 2; ++m) {
    int n = wave;
    f32x4 c = {0.f, 0.f, 0.f, 0.f};
#pragma unroll
    for (int ks = 0; ks < 12; ++ks) {
      bhalf8 a = *(const bhalf8*)&P.w_d1[(n * 16 + l15) * 384 + ks * 32 + lq * 8];
      bhalf8 b = *(const bhalf8*)&xcat[(m * 16 + l15) * 408 + ks * 32 + lq * 8];
      c = mfma16(a, b, c);
    }
    int oc = n * 16 + lq * 4;
    f32x4 bias = *(const f32x4*)&P.d1_b[oc];
    bhalf4 o;
#pragma unroll
    for (int j = 0; j < 4; ++j) o[j] = (bhalf)fmaxf(c[j] + bias[j], 0.f);
    *(bhalf4*)&h1[(m * 16 + l15) * 136 + oc] = o;
  }
  __syncthreads();  // D

  // ---- d2: 2 independent jobs/wave -> h2 (f32) ----
#pragma unroll
  for (int m = 0; m < 2; ++m) {
    int n = wave;
    f32x4 c = {0.f, 0.f, 0.f, 0.f};
#pragma unroll
    for (int ks = 0; ks < 4; ++ks) {
      bhalf8 a = *(const bhalf8*)&P.w_d2[(n * 16 + l15) * 128 + ks * 32 + lq * 8];
      bhalf8 b = *(const bhalf8*)&h1[(m * 16 + l15) * 136 + ks * 32 + lq * 8];
      c = mfma16(a, b, c);
    }
    int oc = n * 16 + lq * 4;
    f32x4 bias = *(const f32x4*)&P.d2_b[oc];
    f32x4 o;
#pragma unroll
    for (int j = 0; j < 4; ++j) o[j] = fmaxf(c[j] + bias[j], 0.f);
    *(f32x4*)&h2[(m * 16 + l15) * 140 + oc] = o;
  }
  __syncthreads();  // E

  // ---- heads: 8 lanes/sample (32 samples x 8 outs = 256 threads) ----
  if (tid < 256) {
    int s = tid >> 3, o = tid & 7;
    const float* wrow = (o < 7) ? &P.pi_w[o * 128] : P.v_w;
    const float* hrow = &h2[s * 140];
    float acc = (o < 7) ? P.pi_b[o] : P.v_b[0];
#pragma unroll
    for (int k = 0; k < 32; ++k) {
      f32x4 wv = *(const f32x4*)&wrow[k * 4];
      f32x4 hv = *(const f32x4*)&hrow[k * 4];
#pragma unroll
      for (int j = 0; j < 4; ++j) acc += wv[j] * hv[j];
    }
    float xm = (o < 7) ? acc : -1e30f;
#pragma unroll
    for (int m = 1; m < 8; m <<= 1) xm = fmaxf(xm, __shfl_xor(xm, m));
    float e = (o < 7) ? __expf(acc - xm) : 0.f;
    float se = e;
#pragma unroll
    for (int m = 1; m < 8; m <<= 1) se += __shfl_xor(se, m);
    if (o < 7) P.out[(size_t)(s0 + s) * 7 + o] = e / se;
    else       P.out[917504 + s0 + s] = acc;  // 131072*7
  }
}

// ---------------- launch ----------------
extern "C" void kernel_launch(void* const* d_in, const int* in_sizes, int n_in,
                              void* d_out, int out_size, void* d_ws, size_t ws_size,
                              hipStream_t stream) {
  (void)in_sizes; (void)n_in; (void)out_size; (void)ws_size;
  const float* const* in = (const float* const*)d_in;
  bhalf* wbf = (bhalf*)d_ws;

  PrepArgs pa;
  const int srcIdx[10] = {5, 9, 11, 15, 21, 25, 27, 31, 35, 37};
  const int lens[10] = {1024, 1024, 1024, 28672, 1024, 1024, 1024, 8192, 49152, 16384};
  const int dsts[10] = {4096, 5120, 6144, 7168, 39936, 40960, 41984, 43008, 55296, 104448};
  for (int i = 0; i < 10; ++i) { pa.src[i] = in[srcIdx[i]]; pa.len[i] = lens[i]; pa.dstOff[i] = dsts[i]; }
  pa.dst = wbf;
  hipLaunchKernelGGL(prep_convert, dim3(424), dim3(256), 0, stream, pa);

  EffArgs ea;
  ea.p_qkv_w = in[3]; ea.p_in_w = in[1]; ea.p_in_b = in[2]; ea.p_qkv_b = in[4]; ea.p_o_b = in[6];
  ea.s_qkv_w = in[19]; ea.s_in_w = in[17]; ea.s_in_b = in[18]; ea.s_qkv_b = in[20]; ea.s_o_b = in[22];
  ea.e_w = in[33]; ea.e_b = in[34];
  ea.dst = wbf;
  hipLaunchKernelGGL(prep_eff, dim3(1), dim3(384), 0, stream, ea);

  Ptrs P;
  P.state = in[0];
  P.p_g1 = in[7];  P.p_b1 = in[8];  P.p_f1b = in[10]; P.p_f2b = in[12];
  P.p_g2 = in[13]; P.p_b2 = in[14]; P.p_out_b = in[16];
  P.s_g1 = in[23]; P.s_b1 = in[24]; P.s_f1b = in[26]; P.s_f2b = in[28];
  P.s_g2 = in[29]; P.s_b2 = in[30]; P.s_out_b = in[32];
  P.d1_b = in[36]; P.d2_b = in[38];
  P.pi_w = in[39]; P.pi_b = in[40]; P.v_w = in[41]; P.v_b = in[42];
  P.A_qp = wbf;          P.A_xp = wbf + 3072;   P.w_o = wbf + 4096;
  P.w_f1 = wbf + 5120;   P.w_f2 = wbf + 6144;   P.w_out = wbf + 7168;
  P.A_qs = wbf + 35840;  P.A_xs = wbf + 38912;  P.w_o2 = wbf + 39936;
  P.w_f12 = wbf + 40960; P.w_f22 = wbf + 41984; P.w_out2 = wbf + 43008;
  P.A_e = wbf + 51200;   P.w_d1 = wbf + 55296;  P.w_d2 = wbf + 104448;
  P.out = (float*)d_out;

  hipLaunchKernelGGL(aac_main, dim3(4096), dim3(512), 0, stream, P);  // 131072/32 blocks
}